// Round 1
// baseline (4809.538 us; speedup 1.0000x reference)
//
#include <hip/hip_runtime.h>
#include <hip/hip_bf16.h>

namespace {

constexpr int B = 1024, T = 512, H = 60, G = 180, NTHR = 192;

__device__ __forceinline__ float sigm(float x) { return 1.f / (1.f + __expf(-x)); }
__device__ __forceinline__ float tanh_fast(float x) {
  x = fminf(fmaxf(x, -15.f), 15.f);
  const float e = __expf(-2.f * x);
  return (1.f - e) / (1.f + e);
}

__device__ __forceinline__ float ldcvt(const float* p) { return *p; }
__device__ __forceinline__ float ldcvt(const __hip_bfloat16* p) { return __bfloat162float(*p); }
__device__ __forceinline__ void stcvt(float* p, float v) { *p = v; }
__device__ __forceinline__ void stcvt(__hip_bfloat16* p, float v) { *p = __float2bfloat16(v); }

// One GRU layer over all T for one batch element per block.
// Thread r (r < 180) owns gate-row r: its Wih row + Whh row live in registers.
// h lives in LDS (wave-uniform broadcast reads). 2 barriers per step.
template <typename TS, bool SCALAR_IN, bool WRITE_YS, bool WRITE_ENC, bool WRITE_PRED>
__global__ __launch_bounds__(NTHR) void gru_layer_kernel(
    const float* __restrict__ xscalar,  // [B][T] when SCALAR_IN
    const TS* __restrict__ xseq,        // [T][B][H] when !SCALAR_IN
    const float* __restrict__ Wih,      // [180][in]
    const float* __restrict__ Whh,      // [180][60]
    const float* __restrict__ bih, const float* __restrict__ bhh,
    const float* __restrict__ h_init,   // nullptr => zeros; index b*180 + j (pre-offset by slot)
    TS* __restrict__ ys_out,            // [T][B][H]
    float* __restrict__ enc_out,        // pre-offset by slot; index b*180 + j
    float* __restrict__ pred_out,       // [B][T]
    const float* __restrict__ lin_W,    // [60]
    const float* __restrict__ lin_b)    // [1]
{
  const int tid = threadIdx.x;
  const int b = blockIdx.x;

  __shared__ __align__(16) float h_sh[64];
  __shared__ __align__(16) float x_sh[2][64];
  __shared__ float Ar[60], Az[60], Nn[60], Hn[60];
  __shared__ float pv[64];
  __shared__ float xs_seq[T];

  // ---- preload this thread's weight rows into registers ----
  float whh[H];
  float wih[H];
  float wih0 = 0.f;
  const int rr = (tid < G) ? tid : 0;
#pragma unroll
  for (int kk = 0; kk < H / 4; ++kk) {
    const float4 w = *(const float4*)&Whh[(size_t)rr * H + kk * 4];
    whh[kk * 4 + 0] = w.x; whh[kk * 4 + 1] = w.y;
    whh[kk * 4 + 2] = w.z; whh[kk * 4 + 3] = w.w;
  }
  if constexpr (SCALAR_IN) {
    wih0 = Wih[rr];  // [180][1]
  } else {
#pragma unroll
    for (int kk = 0; kk < H / 4; ++kk) {
      const float4 w = *(const float4*)&Wih[(size_t)rr * H + kk * 4];
      wih[kk * 4 + 0] = w.x; wih[kk * 4 + 1] = w.y;
      wih[kk * 4 + 2] = w.z; wih[kk * 4 + 3] = w.w;
    }
  }
  const float bi = bih[rr];
  const float bh = bhh[rr];

  float linw = 0.f, linb = 0.f;
  if constexpr (WRITE_PRED) {
    linw = lin_W[tid < H ? tid : 0];
    linb = lin_b[0];
  }

  // ---- init state + first input ----
  if (tid < H) {
    h_sh[tid] = h_init ? h_init[(size_t)b * G + tid] : 0.f;
    if constexpr (!SCALAR_IN) x_sh[0][tid] = ldcvt(&xseq[(size_t)b * H + tid]);
  }
  if constexpr (SCALAR_IN) {
    for (int i = tid; i < T; i += NTHR) xs_seq[i] = xscalar[(size_t)b * T + i];
  }
  __syncthreads();

  const int g = tid / H;       // 0:r 1:z 2:n
  const int j = tid - g * H;

  for (int t = 0; t < T; ++t) {
    const int cur = t & 1, nxt = cur ^ 1;

    // prefetch next step's input (consumed after next barrier)
    float xn = 0.f;
    if constexpr (!SCALAR_IN) {
      if (tid < H && t + 1 < T)
        xn = ldcvt(&xseq[(size_t)(t + 1) * B * H + (size_t)b * H + tid]);
    }

    if (tid < G) {
      float a = bi, c = bh;
      if constexpr (SCALAR_IN) a = fmaf(wih0, xs_seq[t], a);
#pragma unroll
      for (int kk = 0; kk < H / 4; ++kk) {
        const float4 hv = *(const float4*)&h_sh[kk * 4];
        c = fmaf(whh[kk * 4 + 0], hv.x, c);
        c = fmaf(whh[kk * 4 + 1], hv.y, c);
        c = fmaf(whh[kk * 4 + 2], hv.z, c);
        c = fmaf(whh[kk * 4 + 3], hv.w, c);
        if constexpr (!SCALAR_IN) {
          const float4 xv = *(const float4*)&x_sh[cur][kk * 4];
          a = fmaf(wih[kk * 4 + 0], xv.x, a);
          a = fmaf(wih[kk * 4 + 1], xv.y, a);
          a = fmaf(wih[kk * 4 + 2], xv.z, a);
          a = fmaf(wih[kk * 4 + 3], xv.w, a);
        }
      }
      if (g == 0)       Ar[j] = a + c;
      else if (g == 1)  Az[j] = a + c;
      else            { Nn[j] = a; Hn[j] = c; }
    }
    __syncthreads();

    if (tid < H) {
      const float rg = sigm(Ar[tid]);
      const float zg = sigm(Az[tid]);
      const float nv = tanh_fast(fmaf(rg, Hn[tid], Nn[tid]));
      const float hnew = fmaf(zg, h_sh[tid] - nv, nv);  // (1-z)n + z h
      h_sh[tid] = hnew;
      if constexpr (WRITE_YS)
        stcvt(&ys_out[(size_t)t * B * H + (size_t)b * H + tid], hnew);
      if constexpr (!SCALAR_IN) x_sh[nxt][tid] = xn;
      if constexpr (WRITE_PRED) pv[tid] = hnew * linw;
    }
    __syncthreads();

    if constexpr (WRITE_PRED) {
      if (tid < 64) {
        float v = (tid < H) ? pv[tid] : 0.f;
#pragma unroll
        for (int off = 32; off; off >>= 1) v += __shfl_xor(v, off);
        if (tid == 0) pred_out[(size_t)b * T + t] = v + linb;
      }
    }
  }

  if constexpr (WRITE_ENC) {
    if (tid < H) enc_out[(size_t)b * G + tid] = h_sh[tid];
  }
}

template <typename TS>
void launch_all(const float* inputs, const float* outputs,
                const float* eW_ih0, const float* eW_hh0, const float* eb_ih0, const float* eb_hh0,
                const float* eW_ih1, const float* eW_hh1, const float* eb_ih1, const float* eb_hh1,
                const float* eW_ih2, const float* eW_hh2, const float* eb_ih2, const float* eb_hh2,
                const float* c1_Wih, const float* c1_Whh, const float* c1_bih, const float* c1_bhh,
                const float* c2_Wih, const float* c2_Whh, const float* c2_bih, const float* c2_bhh,
                const float* c3_Wih, const float* c3_Whh, const float* c3_bih, const float* c3_bhh,
                const float* lin_W, const float* lin_b,
                float* pred, float* enc, void* d_ws, hipStream_t stream) {
  const size_t seq = (size_t)T * B * H;
  TS* ws0 = (TS*)d_ws;
  TS* ws1 = ws0 + seq;
  const dim3 grid(B), blk(NTHR);

  // encoder
  gru_layer_kernel<TS, true, true, true, false><<<grid, blk, 0, stream>>>(
      inputs, nullptr, eW_ih0, eW_hh0, eb_ih0, eb_hh0, nullptr,
      ws0, enc + 0, nullptr, nullptr, nullptr);
  gru_layer_kernel<TS, false, true, true, false><<<grid, blk, 0, stream>>>(
      nullptr, ws0, eW_ih1, eW_hh1, eb_ih1, eb_hh1, nullptr,
      ws1, enc + 60, nullptr, nullptr, nullptr);
  gru_layer_kernel<TS, false, false, true, false><<<grid, blk, 0, stream>>>(
      nullptr, ws1, eW_ih2, eW_hh2, eb_ih2, eb_hh2, nullptr,
      nullptr, enc + 120, nullptr, nullptr, nullptr);
  // decoder: h1<-enc[2], h2<-enc[1], h3<-enc[0]
  gru_layer_kernel<TS, true, true, false, false><<<grid, blk, 0, stream>>>(
      outputs, nullptr, c1_Wih, c1_Whh, c1_bih, c1_bhh, enc + 120,
      ws0, nullptr, nullptr, nullptr, nullptr);
  gru_layer_kernel<TS, false, true, false, false><<<grid, blk, 0, stream>>>(
      nullptr, ws0, c2_Wih, c2_Whh, c2_bih, c2_bhh, enc + 60,
      ws1, nullptr, nullptr, nullptr, nullptr);
  gru_layer_kernel<TS, false, false, false, true><<<grid, blk, 0, stream>>>(
      nullptr, ws1, c3_Wih, c3_Whh, c3_bih, c3_bhh, enc + 0,
      nullptr, nullptr, pred, lin_W, lin_b);
}

}  // namespace

extern "C" void kernel_launch(void* const* d_in, const int* in_sizes, int n_in,
                              void* d_out, int out_size, void* d_ws, size_t ws_size,
                              hipStream_t stream) {
  const float* inputs  = (const float*)d_in[0];
  const float* outputs = (const float*)d_in[1];
  const float* eW_ih0 = (const float*)d_in[2];  const float* eW_hh0 = (const float*)d_in[3];
  const float* eb_ih0 = (const float*)d_in[4];  const float* eb_hh0 = (const float*)d_in[5];
  const float* eW_ih1 = (const float*)d_in[6];  const float* eW_hh1 = (const float*)d_in[7];
  const float* eb_ih1 = (const float*)d_in[8];  const float* eb_hh1 = (const float*)d_in[9];
  const float* eW_ih2 = (const float*)d_in[10]; const float* eW_hh2 = (const float*)d_in[11];
  const float* eb_ih2 = (const float*)d_in[12]; const float* eb_hh2 = (const float*)d_in[13];
  const float* c1_Wih = (const float*)d_in[14]; const float* c1_Whh = (const float*)d_in[15];
  const float* c1_bih = (const float*)d_in[16]; const float* c1_bhh = (const float*)d_in[17];
  const float* c2_Wih = (const float*)d_in[18]; const float* c2_Whh = (const float*)d_in[19];
  const float* c2_bih = (const float*)d_in[20]; const float* c2_bhh = (const float*)d_in[21];
  const float* c3_Wih = (const float*)d_in[22]; const float* c3_Whh = (const float*)d_in[23];
  const float* c3_bih = (const float*)d_in[24]; const float* c3_bhh = (const float*)d_in[25];
  const float* lin_W  = (const float*)d_in[26]; const float* lin_b  = (const float*)d_in[27];

  float* pred = (float*)d_out;                 // [B][T] = 524288 floats
  float* enc  = pred + (size_t)B * T;          // [B][3][H] = 184320 floats

  const size_t seq = (size_t)T * B * H;
  if (ws_size >= 2 * seq * sizeof(float)) {
    launch_all<float>(inputs, outputs,
                      eW_ih0, eW_hh0, eb_ih0, eb_hh0, eW_ih1, eW_hh1, eb_ih1, eb_hh1,
                      eW_ih2, eW_hh2, eb_ih2, eb_hh2,
                      c1_Wih, c1_Whh, c1_bih, c1_bhh, c2_Wih, c2_Whh, c2_bih, c2_bhh,
                      c3_Wih, c3_Whh, c3_bih, c3_bhh, lin_W, lin_b,
                      pred, enc, d_ws, stream);
  } else {
    // scratch too small for fp32 intermediates -> store them as bf16
    launch_all<__hip_bfloat16>(inputs, outputs,
                      eW_ih0, eW_hh0, eb_ih0, eb_hh0, eW_ih1, eW_hh1, eb_ih1, eb_hh1,
                      eW_ih2, eW_hh2, eb_ih2, eb_hh2,
                      c1_Wih, c1_Whh, c1_bih, c1_bhh, c2_Wih, c2_Whh, c2_bih, c2_bhh,
                      c3_Wih, c3_Whh, c3_bih, c3_bhh, lin_W, lin_b,
                      pred, enc, d_ws, stream);
  }
}

// Round 2
// 4805.072 us; speedup vs baseline: 1.0009x; 1.0009x over previous
//
#include <hip/hip_runtime.h>
#include <hip/hip_bf16.h>

namespace {

constexpr int B = 1024, T = 512, H = 60, G = 180, NTHR = 192;

__device__ __forceinline__ float sigm(float x) { return 1.f / (1.f + __expf(-x)); }
__device__ __forceinline__ float tanh_fast(float x) {
  x = fminf(fmaxf(x, -15.f), 15.f);
  const float e = __expf(-2.f * x);
  return (1.f - e) / (1.f + e);
}

__device__ __forceinline__ float ldcvt(const float* p) { return *p; }
__device__ __forceinline__ float ldcvt(const __hip_bfloat16* p) { return __bfloat162float(*p); }
__device__ __forceinline__ void stcvt(float* p, float v) { *p = v; }
__device__ __forceinline__ void stcvt(__hip_bfloat16* p, float v) { *p = __float2bfloat16(v); }

// One GRU layer over all T for one batch element per block.
// Thread r (r < 180) owns gate-row r: its Wih row + Whh row live in registers.
// h lives in LDS (wave-uniform broadcast reads). 2 barriers per step.
// __launch_bounds__(NTHR, 1): min-waves/EU = 1 so the register allocator may
// use up to 512 VGPRs -- the 120-float weight rows MUST stay in registers.
// (Round 1: default heuristic capped VGPR at 88 and spilled the weights to
// scratch -> 91 GB FETCH_SIZE/dispatch, 18x slowdown vs the no-spill layers.)
template <typename TS, bool SCALAR_IN, bool WRITE_YS, bool WRITE_ENC, bool WRITE_PRED>
__global__ __launch_bounds__(NTHR, 1) void gru_layer_kernel(
    const float* __restrict__ xscalar,  // [B][T] when SCALAR_IN
    const TS* __restrict__ xseq,        // [T][B][H] when !SCALAR_IN
    const float* __restrict__ Wih,      // [180][in]
    const float* __restrict__ Whh,      // [180][60]
    const float* __restrict__ bih, const float* __restrict__ bhh,
    const float* __restrict__ h_init,   // nullptr => zeros; index b*180 + j (pre-offset by slot)
    TS* __restrict__ ys_out,            // [T][B][H]
    float* __restrict__ enc_out,        // pre-offset by slot; index b*180 + j
    float* __restrict__ pred_out,       // [B][T]
    const float* __restrict__ lin_W,    // [60]
    const float* __restrict__ lin_b)    // [1]
{
  const int tid = threadIdx.x;
  const int b = blockIdx.x;

  __shared__ __align__(16) float h_sh[64];
  __shared__ __align__(16) float x_sh[2][64];
  __shared__ float Ar[60], Az[60], Nn[60], Hn[60];
  __shared__ float pv[64];
  __shared__ float xs_seq[T];

  // ---- preload this thread's weight rows into registers ----
  float whh[H];
  float wih[H];
  float wih0 = 0.f;
  const int rr = (tid < G) ? tid : 0;
#pragma unroll
  for (int kk = 0; kk < H / 4; ++kk) {
    const float4 w = *(const float4*)&Whh[(size_t)rr * H + kk * 4];
    whh[kk * 4 + 0] = w.x; whh[kk * 4 + 1] = w.y;
    whh[kk * 4 + 2] = w.z; whh[kk * 4 + 3] = w.w;
  }
  if constexpr (SCALAR_IN) {
    wih0 = Wih[rr];  // [180][1]
  } else {
#pragma unroll
    for (int kk = 0; kk < H / 4; ++kk) {
      const float4 w = *(const float4*)&Wih[(size_t)rr * H + kk * 4];
      wih[kk * 4 + 0] = w.x; wih[kk * 4 + 1] = w.y;
      wih[kk * 4 + 2] = w.z; wih[kk * 4 + 3] = w.w;
    }
  }
  const float bi = bih[rr];
  const float bh = bhh[rr];

  float linw = 0.f, linb = 0.f;
  if constexpr (WRITE_PRED) {
    linw = lin_W[tid < H ? tid : 0];
    linb = lin_b[0];
  }

  // ---- init state + first input ----
  if (tid < H) {
    h_sh[tid] = h_init ? h_init[(size_t)b * G + tid] : 0.f;
    if constexpr (!SCALAR_IN) x_sh[0][tid] = ldcvt(&xseq[(size_t)b * H + tid]);
  }
  if constexpr (SCALAR_IN) {
    for (int i = tid; i < T; i += NTHR) xs_seq[i] = xscalar[(size_t)b * T + i];
  }
  __syncthreads();

  const int g = tid / H;       // 0:r 1:z 2:n
  const int j = tid - g * H;

  for (int t = 0; t < T; ++t) {
    const int cur = t & 1, nxt = cur ^ 1;

    // prefetch next step's input (consumed after next barrier)
    float xn = 0.f;
    if constexpr (!SCALAR_IN) {
      if (tid < H && t + 1 < T)
        xn = ldcvt(&xseq[(size_t)(t + 1) * B * H + (size_t)b * H + tid]);
    }

    if (tid < G) {
      float a = bi, c = bh;
      if constexpr (SCALAR_IN) a = fmaf(wih0, xs_seq[t], a);
#pragma unroll
      for (int kk = 0; kk < H / 4; ++kk) {
        const float4 hv = *(const float4*)&h_sh[kk * 4];
        c = fmaf(whh[kk * 4 + 0], hv.x, c);
        c = fmaf(whh[kk * 4 + 1], hv.y, c);
        c = fmaf(whh[kk * 4 + 2], hv.z, c);
        c = fmaf(whh[kk * 4 + 3], hv.w, c);
        if constexpr (!SCALAR_IN) {
          const float4 xv = *(const float4*)&x_sh[cur][kk * 4];
          a = fmaf(wih[kk * 4 + 0], xv.x, a);
          a = fmaf(wih[kk * 4 + 1], xv.y, a);
          a = fmaf(wih[kk * 4 + 2], xv.z, a);
          a = fmaf(wih[kk * 4 + 3], xv.w, a);
        }
      }
      if (g == 0)       Ar[j] = a + c;
      else if (g == 1)  Az[j] = a + c;
      else            { Nn[j] = a; Hn[j] = c; }
    }
    __syncthreads();

    if (tid < H) {
      const float rg = sigm(Ar[tid]);
      const float zg = sigm(Az[tid]);
      const float nv = tanh_fast(fmaf(rg, Hn[tid], Nn[tid]));
      const float hnew = fmaf(zg, h_sh[tid] - nv, nv);  // (1-z)n + z h
      h_sh[tid] = hnew;
      if constexpr (WRITE_YS)
        stcvt(&ys_out[(size_t)t * B * H + (size_t)b * H + tid], hnew);
      if constexpr (!SCALAR_IN) x_sh[nxt][tid] = xn;
      if constexpr (WRITE_PRED) pv[tid] = hnew * linw;
    }
    __syncthreads();

    if constexpr (WRITE_PRED) {
      if (tid < 64) {
        float v = (tid < H) ? pv[tid] : 0.f;
#pragma unroll
        for (int off = 32; off; off >>= 1) v += __shfl_xor(v, off);
        if (tid == 0) pred_out[(size_t)b * T + t] = v + linb;
      }
    }
  }

  if constexpr (WRITE_ENC) {
    if (tid < H) enc_out[(size_t)b * G + tid] = h_sh[tid];
  }
}

template <typename TS>
void launch_all(const float* inputs, const float* outputs,
                const float* eW_ih0, const float* eW_hh0, const float* eb_ih0, const float* eb_hh0,
                const float* eW_ih1, const float* eW_hh1, const float* eb_ih1, const float* eb_hh1,
                const float* eW_ih2, const float* eW_hh2, const float* eb_ih2, const float* eb_hh2,
                const float* c1_Wih, const float* c1_Whh, const float* c1_bih, const float* c1_bhh,
                const float* c2_Wih, const float* c2_Whh, const float* c2_bih, const float* c2_bhh,
                const float* c3_Wih, const float* c3_Whh, const float* c3_bih, const float* c3_bhh,
                const float* lin_W, const float* lin_b,
                float* pred, float* enc, void* d_ws, hipStream_t stream) {
  const size_t seq = (size_t)T * B * H;
  TS* ws0 = (TS*)d_ws;
  TS* ws1 = ws0 + seq;
  const dim3 grid(B), blk(NTHR);

  // encoder
  gru_layer_kernel<TS, true, true, true, false><<<grid, blk, 0, stream>>>(
      inputs, nullptr, eW_ih0, eW_hh0, eb_ih0, eb_hh0, nullptr,
      ws0, enc + 0, nullptr, nullptr, nullptr);
  gru_layer_kernel<TS, false, true, true, false><<<grid, blk, 0, stream>>>(
      nullptr, ws0, eW_ih1, eW_hh1, eb_ih1, eb_hh1, nullptr,
      ws1, enc + 60, nullptr, nullptr, nullptr);
  gru_layer_kernel<TS, false, false, true, false><<<grid, blk, 0, stream>>>(
      nullptr, ws1, eW_ih2, eW_hh2, eb_ih2, eb_hh2, nullptr,
      nullptr, enc + 120, nullptr, nullptr, nullptr);
  // decoder: h1<-enc[2], h2<-enc[1], h3<-enc[0]
  gru_layer_kernel<TS, true, true, false, false><<<grid, blk, 0, stream>>>(
      outputs, nullptr, c1_Wih, c1_Whh, c1_bih, c1_bhh, enc + 120,
      ws0, nullptr, nullptr, nullptr, nullptr);
  gru_layer_kernel<TS, false, true, false, false><<<grid, blk, 0, stream>>>(
      nullptr, ws0, c2_Wih, c2_Whh, c2_bih, c2_bhh, enc + 60,
      ws1, nullptr, nullptr, nullptr, nullptr);
  gru_layer_kernel<TS, false, false, false, true><<<grid, blk, 0, stream>>>(
      nullptr, ws1, c3_Wih, c3_Whh, c3_bih, c3_bhh, enc + 0,
      nullptr, nullptr, pred, lin_W, lin_b);
}

}  // namespace

extern "C" void kernel_launch(void* const* d_in, const int* in_sizes, int n_in,
                              void* d_out, int out_size, void* d_ws, size_t ws_size,
                              hipStream_t stream) {
  const float* inputs  = (const float*)d_in[0];
  const float* outputs = (const float*)d_in[1];
  const float* eW_ih0 = (const float*)d_in[2];  const float* eW_hh0 = (const float*)d_in[3];
  const float* eb_ih0 = (const float*)d_in[4];  const float* eb_hh0 = (const float*)d_in[5];
  const float* eW_ih1 = (const float*)d_in[6];  const float* eW_hh1 = (const float*)d_in[7];
  const float* eb_ih1 = (const float*)d_in[8];  const float* eb_hh1 = (const float*)d_in[9];
  const float* eW_ih2 = (const float*)d_in[10]; const float* eW_hh2 = (const float*)d_in[11];
  const float* eb_ih2 = (const float*)d_in[12]; const float* eb_hh2 = (const float*)d_in[13];
  const float* c1_Wih = (const float*)d_in[14]; const float* c1_Whh = (const float*)d_in[15];
  const float* c1_bih = (const float*)d_in[16]; const float* c1_bhh = (const float*)d_in[17];
  const float* c2_Wih = (const float*)d_in[18]; const float* c2_Whh = (const float*)d_in[19];
  const float* c2_bih = (const float*)d_in[20]; const float* c2_bhh = (const float*)d_in[21];
  const float* c3_Wih = (const float*)d_in[22]; const float* c3_Whh = (const float*)d_in[23];
  const float* c3_bih = (const float*)d_in[24]; const float* c3_bhh = (const float*)d_in[25];
  const float* lin_W  = (const float*)d_in[26]; const float* lin_b  = (const float*)d_in[27];

  float* pred = (float*)d_out;                 // [B][T] = 524288 floats
  float* enc  = pred + (size_t)B * T;          // [B][3][H] = 184320 floats

  const size_t seq = (size_t)T * B * H;
  if (ws_size >= 2 * seq * sizeof(float)) {
    launch_all<float>(inputs, outputs,
                      eW_ih0, eW_hh0, eb_ih0, eb_hh0, eW_ih1, eW_hh1, eb_ih1, eb_hh1,
                      eW_ih2, eW_hh2, eb_ih2, eb_hh2,
                      c1_Wih, c1_Whh, c1_bih, c1_bhh, c2_Wih, c2_Whh, c2_bih, c2_bhh,
                      c3_Wih, c3_Whh, c3_bih, c3_bhh, lin_W, lin_b,
                      pred, enc, d_ws, stream);
  } else {
    // scratch too small for fp32 intermediates -> store them as bf16
    launch_all<__hip_bfloat16>(inputs, outputs,
                      eW_ih0, eW_hh0, eb_ih0, eb_hh0, eW_ih1, eW_hh1, eb_ih1, eb_hh1,
                      eW_ih2, eW_hh2, eb_ih2, eb_hh2,
                      c1_Wih, c1_Whh, c1_bih, c1_bhh, c2_Wih, c2_Whh, c2_bih, c2_bhh,
                      c3_Wih, c3_Whh, c3_bih, c3_bhh, lin_W, lin_b,
                      pred, enc, d_ws, stream);
  }
}